// Round 1
// 844.577 us; speedup vs baseline: 1.0567x; 1.0567x over previous
//
#include <hip/hip_runtime.h>

#define NB 256
#define NT 1024
#define NH 512
#define NI 3
#define NO 3

// DPP-based wave64 reduction: after the ladder, lane 63 holds the full sum.
template<int CTRL>
__device__ __forceinline__ float dpp_add(float x) {
  int y = __builtin_amdgcn_update_dpp(0, __float_as_int(x), CTRL, 0xf, 0xf, false);
  return x + __int_as_float(y);
}

__device__ __forceinline__ float wave_sum63(float x) {
  x = dpp_add<0x111>(x);  // row_shr:1
  x = dpp_add<0x112>(x);  // row_shr:2
  x = dpp_add<0x114>(x);  // row_shr:4
  x = dpp_add<0x118>(x);  // row_shr:8
  x = dpp_add<0x142>(x);  // row_bcast:15
  x = dpp_add<0x143>(x);  // row_bcast:31
  return x;               // lane 63 = total
}

__device__ __forceinline__ float fast_tanh(float x) {
  float e = __builtin_amdgcn_exp2f(x * 2.885390081777927f);
  float r = __builtin_amdgcn_rcpf(e + 1.0f);
  return fmaf(-2.0f, r, 1.0f);
}

// 4 waves per block:
//   waves 0,1 : serial rank-4 recurrence (hidden split 256/256), log p_t to LDS
//   waves 2,3 : trail 2 steps behind; recompute h_t from p_used[t], write r & y
__global__ __launch_bounds__(256, 1)
void lowrank_rnn_kernel(const float* __restrict__ x,
                        const float* __restrict__ hidden,
                        const float* __restrict__ U,
                        const float* __restrict__ V,
                        const float* __restrict__ W_in,
                        const float* __restrict__ b_in,
                        const float* __restrict__ W_out,
                        const float* __restrict__ b_out,
                        float* __restrict__ out_y,   // [B,T,NO]
                        float* __restrict__ out_h,   // [B,NH]
                        float* __restrict__ out_r) { // [B,T,NH]
  const int b = blockIdx.x;
  const int tid = threadIdx.x;
  const int lane = tid & 63;
  const int wid = tid >> 6;

  __shared__ float xs[NT * NI];        // 12 KB
  __shared__ float4 p_used[NT + 1];    // 16.4 KB: p consumed by step t
  __shared__ float4 exch[2][2];        // [parity][serial-wave] partial p

  // ---- stage x[b] into LDS (coalesced float4, all 4 waves) ----
  {
    const float4* src = (const float4*)(x + (size_t)b * NT * NI);
    float4* dst = (float4*)xs;
#pragma unroll
    for (int i = 0; i < (NT * NI / 4) / 256; ++i)  // 3 iters
      dst[i * 256 + tid] = src[i * 256 + tid];
  }
  __syncthreads();  // sync A

  if (wid < 2) {
    // ================= serial waves: p-recurrence only =================
    // wave 'wid' owns hidden half: h = wid*256 + 4*lane + j, j in [0,4)
    float Uv[4][4], Vv[4][4];
#pragma unroll
    for (int r = 0; r < 4; ++r) {
      float4 u = ((const float4*)U)[r * 128 + wid * 64 + lane];
      Uv[r][0] = u.x; Uv[r][1] = u.y; Uv[r][2] = u.z; Uv[r][3] = u.w;
      float4 v = ((const float4*)V)[r * 128 + wid * 64 + lane];
      Vv[r][0] = v.x; Vv[r][1] = v.y; Vv[r][2] = v.z; Vv[r][3] = v.w;
    }
    float Wi[4][3];
#pragma unroll
    for (int j = 0; j < 4; ++j) {
      int h = wid * 256 + 4 * lane + j;
      Wi[j][0] = W_in[h * 3 + 0];
      Wi[j][1] = W_in[h * 3 + 1];
      Wi[j][2] = W_in[h * 3 + 2];
    }
    float bin[4];
    {
      float4 bb = ((const float4*)b_in)[wid * 64 + lane];
      bin[0] = bb.x; bin[1] = bb.y; bin[2] = bb.z; bin[3] = bb.w;
    }
    float hv[4];
    {
      float4 h4 = ((const float4*)(hidden + (size_t)b * NH))[wid * 64 + lane];
      hv[0] = h4.x; hv[1] = h4.y; hv[2] = h4.z; hv[3] = h4.w;
    }

    // ---- initial p = V @ h0 (cross-wave combine) ----
    {
      float s0 = 0.f, s1 = 0.f, s2 = 0.f, s3 = 0.f;
#pragma unroll
      for (int j = 0; j < 4; ++j) {
        s0 = fmaf(hv[j], Vv[0][j], s0);
        s1 = fmaf(hv[j], Vv[1][j], s1);
        s2 = fmaf(hv[j], Vv[2][j], s2);
        s3 = fmaf(hv[j], Vv[3][j], s3);
      }
      s0 = wave_sum63(s0); s1 = wave_sum63(s1);
      s2 = wave_sum63(s2); s3 = wave_sum63(s3);
      if (lane == 63) exch[1][wid] = make_float4(s0, s1, s2, s3);
    }
    __syncthreads();  // sync B
    float p0, p1, p2, p3;
    {
      float4 A = exch[1][0], Bv = exch[1][1];
      p0 = A.x + Bv.x; p1 = A.y + Bv.y; p2 = A.z + Bv.z; p3 = A.w + Bv.w;
      if (tid == 0) p_used[0] = make_float4(p0, p1, p2, p3);
    }

    float cx0 = xs[0], cx1 = xs[1], cx2 = xs[2];

    for (int t = 0; t < NT + 2; ++t) {
      if (t < NT) {
        float a[4];
#pragma unroll
        for (int j = 0; j < 4; ++j) {
          float v = bin[j];
          v = fmaf(cx0, Wi[j][0], v);
          v = fmaf(cx1, Wi[j][1], v);
          v = fmaf(cx2, Wi[j][2], v);
          v = fmaf(p0, Uv[0][j], v);
          v = fmaf(p1, Uv[1][j], v);
          v = fmaf(p2, Uv[2][j], v);
          v = fmaf(p3, Uv[3][j], v);
          a[j] = v;
        }
        // prefetch next step's x while tanh/reduce run
        if (t + 1 < NT) {
          cx0 = xs[(t + 1) * 3 + 0];
          cx1 = xs[(t + 1) * 3 + 1];
          cx2 = xs[(t + 1) * 3 + 2];
        }
#pragma unroll
        for (int j = 0; j < 4; ++j) hv[j] = fast_tanh(a[j]);

        float s0 = 0.f, s1 = 0.f, s2 = 0.f, s3 = 0.f;
#pragma unroll
        for (int j = 0; j < 4; ++j) {
          s0 = fmaf(hv[j], Vv[0][j], s0);
          s1 = fmaf(hv[j], Vv[1][j], s1);
          s2 = fmaf(hv[j], Vv[2][j], s2);
          s3 = fmaf(hv[j], Vv[3][j], s3);
        }
        s0 = wave_sum63(s0); s1 = wave_sum63(s1);
        s2 = wave_sum63(s2); s3 = wave_sum63(s3);
        if (lane == 63) exch[t & 1][wid] = make_float4(s0, s1, s2, s3);
      }
      __syncthreads();  // per-step barrier (all 4 waves)
      if (t < NT) {
        float4 A = exch[t & 1][0], Bv = exch[t & 1][1];
        p0 = A.x + Bv.x; p1 = A.y + Bv.y; p2 = A.z + Bv.z; p3 = A.w + Bv.w;
        if (tid == 0) p_used[t + 1] = make_float4(p0, p1, p2, p3);
      }
    }

    // h_last = h_{T-1} (each serial wave writes its half)
    float4* hp = (float4*)(out_h + (size_t)b * NH);
    hp[wid * 64 + lane] = make_float4(hv[0], hv[1], hv[2], hv[3]);
  } else {
    // ================= writer waves: recompute h, emit r & y =================
    // full-width mapping (as original): j<4 : h=4*lane+j ; j>=4 : h=256+4*lane+(j-4)
    float Uv[4][8];
#pragma unroll
    for (int r = 0; r < 4; ++r) {
      float4 u0 = ((const float4*)U)[r * 128 + lane];
      float4 u1 = ((const float4*)U)[r * 128 + 64 + lane];
      Uv[r][0] = u0.x; Uv[r][1] = u0.y; Uv[r][2] = u0.z; Uv[r][3] = u0.w;
      Uv[r][4] = u1.x; Uv[r][5] = u1.y; Uv[r][6] = u1.z; Uv[r][7] = u1.w;
    }
    float Wi[8][3];
#pragma unroll
    for (int j = 0; j < 8; ++j) {
      int h = (j < 4) ? (4 * lane + j) : (256 + 4 * lane + (j - 4));
      Wi[j][0] = W_in[h * 3 + 0];
      Wi[j][1] = W_in[h * 3 + 1];
      Wi[j][2] = W_in[h * 3 + 2];
    }
    float bin[8];
    {
      float4 b0 = ((const float4*)b_in)[lane];
      float4 b1 = ((const float4*)b_in)[64 + lane];
      bin[0] = b0.x; bin[1] = b0.y; bin[2] = b0.z; bin[3] = b0.w;
      bin[4] = b1.x; bin[5] = b1.y; bin[6] = b1.z; bin[7] = b1.w;
    }
    float Wo[3][8];
#pragma unroll
    for (int o = 0; o < 3; ++o) {
      float4 w0 = ((const float4*)W_out)[o * 128 + lane];
      float4 w1 = ((const float4*)W_out)[o * 128 + 64 + lane];
      Wo[o][0] = w0.x; Wo[o][1] = w0.y; Wo[o][2] = w0.z; Wo[o][3] = w0.w;
      Wo[o][4] = w1.x; Wo[o][5] = w1.y; Wo[o][6] = w1.z; Wo[o][7] = w1.w;
    }
    const float bo0 = b_out[0], bo1 = b_out[1], bo2 = b_out[2];

    __syncthreads();  // sync B (match serial waves)

    float* rbase = out_r + (size_t)b * NT * NH;
    float* ybase = out_y + (size_t)b * NT * NO;

    for (int t = 0; t < NT + 2; ++t) {
      const int tp = t - 2;  // step being finalized (published 2 barriers ago)
      if (tp >= 0 && (tp & 1) == (wid & 1)) {  // wave2: even t, wave3: odd t
        float4 pu = p_used[tp];
        float cx0 = xs[tp * 3 + 0], cx1 = xs[tp * 3 + 1], cx2 = xs[tp * 3 + 2];
        float hvv[8];
#pragma unroll
        for (int j = 0; j < 8; ++j) {
          float v = bin[j];
          v = fmaf(cx0, Wi[j][0], v);
          v = fmaf(cx1, Wi[j][1], v);
          v = fmaf(cx2, Wi[j][2], v);
          v = fmaf(pu.x, Uv[0][j], v);
          v = fmaf(pu.y, Uv[1][j], v);
          v = fmaf(pu.z, Uv[2][j], v);
          v = fmaf(pu.w, Uv[3][j], v);
          hvv[j] = fast_tanh(v);
        }
        // store r_out[b][tp][:] — two coalesced dwordx4
        float4* rp = (float4*)(rbase + (size_t)tp * NH);
        rp[lane] = make_float4(hvv[0], hvv[1], hvv[2], hvv[3]);
        rp[64 + lane] = make_float4(hvv[4], hvv[5], hvv[6], hvv[7]);

        float q0 = 0.f, q1 = 0.f, q2 = 0.f;
#pragma unroll
        for (int j = 0; j < 8; ++j) {
          q0 = fmaf(hvv[j], Wo[0][j], q0);
          q1 = fmaf(hvv[j], Wo[1][j], q1);
          q2 = fmaf(hvv[j], Wo[2][j], q2);
        }
        q0 = wave_sum63(q0);
        q1 = wave_sum63(q1);
        q2 = wave_sum63(q2);
        if (lane == 63) {
          float* yp = ybase + tp * NO;
          yp[0] = q0 + bo0;
          yp[1] = q1 + bo1;
          yp[2] = q2 + bo2;
        }
      }
      __syncthreads();  // per-step barrier (match serial waves)
    }
  }
}

extern "C" void kernel_launch(void* const* d_in, const int* in_sizes, int n_in,
                              void* d_out, int out_size, void* d_ws, size_t ws_size,
                              hipStream_t stream) {
  const float* x      = (const float*)d_in[0];
  const float* hidden = (const float*)d_in[1];
  const float* U      = (const float*)d_in[2];
  const float* V      = (const float*)d_in[3];
  const float* W_in   = (const float*)d_in[4];
  const float* b_in   = (const float*)d_in[5];
  const float* W_out  = (const float*)d_in[6];
  const float* b_out  = (const float*)d_in[7];

  float* out = (float*)d_out;
  float* out_y = out;                                  // [B,T,3]
  float* out_h = out + (size_t)NB * NT * NO;           // [B,512]
  float* out_r = out_h + (size_t)NB * NH;              // [B,T,512]

  hipLaunchKernelGGL(lowrank_rnn_kernel, dim3(NB), dim3(256), 0, stream,
                     x, hidden, U, V, W_in, b_in, W_out, b_out,
                     out_y, out_h, out_r);
}

// Round 2
// 752.499 us; speedup vs baseline: 1.1860x; 1.1224x over previous
//
#include <hip/hip_runtime.h>

#define NB 256
#define NT 1024
#define NH 512
#define NI 3
#define NO 3
#define CH 16              // steps per chunk
#define NC (NT / CH)       // 64 chunks

// DPP-based wave64 reduction: after the ladder, lane 63 holds the full sum.
template<int CTRL>
__device__ __forceinline__ float dpp_add(float x) {
  int y = __builtin_amdgcn_update_dpp(0, __float_as_int(x), CTRL, 0xf, 0xf, false);
  return x + __int_as_float(y);
}

__device__ __forceinline__ float wave_sum63(float x) {
  x = dpp_add<0x111>(x);  // row_shr:1
  x = dpp_add<0x112>(x);  // row_shr:2
  x = dpp_add<0x114>(x);  // row_shr:4
  x = dpp_add<0x118>(x);  // row_shr:8
  x = dpp_add<0x142>(x);  // row_bcast:15
  x = dpp_add<0x143>(x);  // row_bcast:31
  return x;               // lane 63 = total
}

__device__ __forceinline__ float bcast_lane63(float x) {
  return __int_as_float(__builtin_amdgcn_readlane(__float_as_int(x), 63));
}

__device__ __forceinline__ float fast_tanh(float x) {
  float e = __builtin_amdgcn_exp2f(x * 2.885390081777927f);
  float r = __builtin_amdgcn_rcpf(e + 1.0f);
  return fmaf(-2.0f, r, 1.0f);
}

// 4 waves / block, chunked producer-consumer pipeline (barrier every CH steps):
//   wave 0: serial recurrence, full 512 width; consumes c_buf chunk k,
//           publishes h_buf chunk k. ONLY wave that runs tanh.
//   wave 1: precomputes c_t = W_in x_t + b_in for chunk k+1.
//   waves 2,3: consume h_buf chunk k-1 -> write r, reduce+write y.
__global__ __launch_bounds__(256, 1)
void lowrank_rnn_kernel(const float* __restrict__ x,
                        const float* __restrict__ hidden,
                        const float* __restrict__ U,
                        const float* __restrict__ V,
                        const float* __restrict__ W_in,
                        const float* __restrict__ b_in,
                        const float* __restrict__ W_out,
                        const float* __restrict__ b_out,
                        float* __restrict__ out_y,   // [B,T,NO]
                        float* __restrict__ out_h,   // [B,NH]
                        float* __restrict__ out_r) { // [B,T,NH]
  const int b = blockIdx.x;
  const int tid = threadIdx.x;
  const int lane = tid & 63;
  const int wid = tid >> 6;

  __shared__ float c_buf[2][CH][NH];  // 64 KB: input projection, chunk double-buffer
  __shared__ float h_buf[2][CH][NH];  // 64 KB: hidden states, chunk double-buffer

  // ---- per-wave persistent state (only the owning wave initializes/uses) ----
  float Uv[4][8], Vv[4][8];           // wave 0
  float hv[8];                        // wave 0
  float p0 = 0.f, p1 = 0.f, p2 = 0.f, p3 = 0.f;  // wave 0
  float Wi[8][3], bin[8];             // wave 1
  float Wo[3][8];                     // waves 2,3
  float bo0 = 0.f, bo1 = 0.f, bo2 = 0.f;

  // Lane j-slot -> hidden index: j<4 : h = 4*lane+j ; j>=4 : h = 256+4*lane+(j-4)

  // =================== prologue (no barriers inside) ===================
  if (wid == 0) {
#pragma unroll
    for (int r = 0; r < 4; ++r) {
      float4 u0 = ((const float4*)U)[r * 128 + lane];
      float4 u1 = ((const float4*)U)[r * 128 + 64 + lane];
      Uv[r][0] = u0.x; Uv[r][1] = u0.y; Uv[r][2] = u0.z; Uv[r][3] = u0.w;
      Uv[r][4] = u1.x; Uv[r][5] = u1.y; Uv[r][6] = u1.z; Uv[r][7] = u1.w;
      float4 v0 = ((const float4*)V)[r * 128 + lane];
      float4 v1 = ((const float4*)V)[r * 128 + 64 + lane];
      Vv[r][0] = v0.x; Vv[r][1] = v0.y; Vv[r][2] = v0.z; Vv[r][3] = v0.w;
      Vv[r][4] = v1.x; Vv[r][5] = v1.y; Vv[r][6] = v1.z; Vv[r][7] = v1.w;
    }
    {
      const float4* h4 = (const float4*)(hidden + (size_t)b * NH);
      float4 h0 = h4[lane];
      float4 h1 = h4[64 + lane];
      hv[0] = h0.x; hv[1] = h0.y; hv[2] = h0.z; hv[3] = h0.w;
      hv[4] = h1.x; hv[5] = h1.y; hv[6] = h1.z; hv[7] = h1.w;
    }
    // initial p = V @ h0
    float s0 = 0.f, s1 = 0.f, s2 = 0.f, s3 = 0.f;
#pragma unroll
    for (int j = 0; j < 8; ++j) {
      s0 = fmaf(hv[j], Vv[0][j], s0);
      s1 = fmaf(hv[j], Vv[1][j], s1);
      s2 = fmaf(hv[j], Vv[2][j], s2);
      s3 = fmaf(hv[j], Vv[3][j], s3);
    }
    p0 = bcast_lane63(wave_sum63(s0));
    p1 = bcast_lane63(wave_sum63(s1));
    p2 = bcast_lane63(wave_sum63(s2));
    p3 = bcast_lane63(wave_sum63(s3));
  } else if (wid == 1) {
#pragma unroll
    for (int j = 0; j < 8; ++j) {
      int h = (j < 4) ? (4 * lane + j) : (256 + 4 * lane + (j - 4));
      Wi[j][0] = W_in[h * 3 + 0];
      Wi[j][1] = W_in[h * 3 + 1];
      Wi[j][2] = W_in[h * 3 + 2];
    }
    {
      float4 b0 = ((const float4*)b_in)[lane];
      float4 b1 = ((const float4*)b_in)[64 + lane];
      bin[0] = b0.x; bin[1] = b0.y; bin[2] = b0.z; bin[3] = b0.w;
      bin[4] = b1.x; bin[5] = b1.y; bin[6] = b1.z; bin[7] = b1.w;
    }
    // fill c chunk 0
    const float* xb = x + (size_t)b * NT * NI;
    for (int s = 0; s < CH; ++s) {
      const float* xp = xb + s * NI;
      float x0 = xp[0], x1 = xp[1], x2 = xp[2];
      float cv[8];
#pragma unroll
      for (int j = 0; j < 8; ++j) {
        float v = bin[j];
        v = fmaf(x0, Wi[j][0], v);
        v = fmaf(x1, Wi[j][1], v);
        v = fmaf(x2, Wi[j][2], v);
        cv[j] = v;
      }
      *(float4*)&c_buf[0][s][4 * lane] = make_float4(cv[0], cv[1], cv[2], cv[3]);
      *(float4*)&c_buf[0][s][256 + 4 * lane] = make_float4(cv[4], cv[5], cv[6], cv[7]);
    }
  } else {
#pragma unroll
    for (int o = 0; o < 3; ++o) {
      float4 w0 = ((const float4*)W_out)[o * 128 + lane];
      float4 w1 = ((const float4*)W_out)[o * 128 + 64 + lane];
      Wo[o][0] = w0.x; Wo[o][1] = w0.y; Wo[o][2] = w0.z; Wo[o][3] = w0.w;
      Wo[o][4] = w1.x; Wo[o][5] = w1.y; Wo[o][6] = w1.z; Wo[o][7] = w1.w;
    }
    bo0 = b_out[0]; bo1 = b_out[1]; bo2 = b_out[2];
  }

  __syncthreads();  // chunk 0's c ready

  float* rbase = out_r + (size_t)b * NT * NH;
  float* ybase = out_y + (size_t)b * NT * NO;

  // =================== chunked pipeline: NC+1 intervals ===================
  for (int k = 0; k <= NC; ++k) {
    if (wid == 0) {
      if (k < NC) {
        const float (*cc)[NH] = c_buf[k & 1];
        float (*hh)[NH] = h_buf[k & 1];
        float4 ca = *(const float4*)&cc[0][4 * lane];
        float4 cb = *(const float4*)&cc[0][256 + 4 * lane];
#pragma unroll 4
        for (int s = 0; s < CH; ++s) {
          // a[j] = c[j] + U^T p   (same FP order as before: c chain, then p0..p3)
          float a[8];
          a[0] = fmaf(p3, Uv[3][0], fmaf(p2, Uv[2][0], fmaf(p1, Uv[1][0], fmaf(p0, Uv[0][0], ca.x))));
          a[1] = fmaf(p3, Uv[3][1], fmaf(p2, Uv[2][1], fmaf(p1, Uv[1][1], fmaf(p0, Uv[0][1], ca.y))));
          a[2] = fmaf(p3, Uv[3][2], fmaf(p2, Uv[2][2], fmaf(p1, Uv[1][2], fmaf(p0, Uv[0][2], ca.z))));
          a[3] = fmaf(p3, Uv[3][3], fmaf(p2, Uv[2][3], fmaf(p1, Uv[1][3], fmaf(p0, Uv[0][3], ca.w))));
          a[4] = fmaf(p3, Uv[3][4], fmaf(p2, Uv[2][4], fmaf(p1, Uv[1][4], fmaf(p0, Uv[0][4], cb.x))));
          a[5] = fmaf(p3, Uv[3][5], fmaf(p2, Uv[2][5], fmaf(p1, Uv[1][5], fmaf(p0, Uv[0][5], cb.y))));
          a[6] = fmaf(p3, Uv[3][6], fmaf(p2, Uv[2][6], fmaf(p1, Uv[1][6], fmaf(p0, Uv[0][6], cb.z))));
          a[7] = fmaf(p3, Uv[3][7], fmaf(p2, Uv[2][7], fmaf(p1, Uv[1][7], fmaf(p0, Uv[0][7], cb.w))));
          // prefetch next step's c (latency hides under tanh + reduce)
          if (s + 1 < CH) {
            ca = *(const float4*)&cc[s + 1][4 * lane];
            cb = *(const float4*)&cc[s + 1][256 + 4 * lane];
          }
#pragma unroll
          for (int j = 0; j < 8; ++j) hv[j] = fast_tanh(a[j]);
          // publish h (fire-and-forget; visible to consumers after next barrier)
          *(float4*)&hh[s][4 * lane] = make_float4(hv[0], hv[1], hv[2], hv[3]);
          *(float4*)&hh[s][256 + 4 * lane] = make_float4(hv[4], hv[5], hv[6], hv[7]);
          // p' = V h
          float s0 = 0.f, s1 = 0.f, s2 = 0.f, s3 = 0.f;
#pragma unroll
          for (int j = 0; j < 8; ++j) {
            s0 = fmaf(hv[j], Vv[0][j], s0);
            s1 = fmaf(hv[j], Vv[1][j], s1);
            s2 = fmaf(hv[j], Vv[2][j], s2);
            s3 = fmaf(hv[j], Vv[3][j], s3);
          }
          s0 = wave_sum63(s0);
          s1 = wave_sum63(s1);
          s2 = wave_sum63(s2);
          s3 = wave_sum63(s3);
          p0 = bcast_lane63(s0);
          p1 = bcast_lane63(s1);
          p2 = bcast_lane63(s2);
          p3 = bcast_lane63(s3);
        }
      }
    } else if (wid == 1) {
      if (k + 1 < NC) {
        // fill c chunk k+1 while serial wave consumes chunk k
        const int tbase = (k + 1) * CH;
        float (*cdst)[NH] = c_buf[(k + 1) & 1];
        const float* xb = x + ((size_t)b * NT + tbase) * NI;
        for (int s = 0; s < CH; ++s) {
          const float* xp = xb + s * NI;
          float x0 = xp[0], x1 = xp[1], x2 = xp[2];
          float cv[8];
#pragma unroll
          for (int j = 0; j < 8; ++j) {
            float v = bin[j];
            v = fmaf(x0, Wi[j][0], v);
            v = fmaf(x1, Wi[j][1], v);
            v = fmaf(x2, Wi[j][2], v);
            cv[j] = v;
          }
          *(float4*)&cdst[s][4 * lane] = make_float4(cv[0], cv[1], cv[2], cv[3]);
          *(float4*)&cdst[s][256 + 4 * lane] = make_float4(cv[4], cv[5], cv[6], cv[7]);
        }
      }
    } else {
      if (k >= 1) {
        // consume h chunk k-1: write r, reduce+write y. wave2: s 0..7, wave3: s 8..15
        const float (*hb)[NH] = h_buf[(k - 1) & 1];
        const int tb = (k - 1) * CH;
#pragma unroll 2
        for (int si = 0; si < CH / 2; ++si) {
          const int s = (wid - 2) * (CH / 2) + si;
          const int t = tb + s;
          float4 h0 = *(const float4*)&hb[s][4 * lane];
          float4 h1 = *(const float4*)&hb[s][256 + 4 * lane];
          // store r_out[b][t][:]
          float4* rp = (float4*)(rbase + (size_t)t * NH);
          rp[lane] = h0;
          rp[64 + lane] = h1;
          float hvv[8] = {h0.x, h0.y, h0.z, h0.w, h1.x, h1.y, h1.z, h1.w};
          float q0 = 0.f, q1 = 0.f, q2 = 0.f;
#pragma unroll
          for (int j = 0; j < 8; ++j) {
            q0 = fmaf(hvv[j], Wo[0][j], q0);
            q1 = fmaf(hvv[j], Wo[1][j], q1);
            q2 = fmaf(hvv[j], Wo[2][j], q2);
          }
          q0 = wave_sum63(q0);
          q1 = wave_sum63(q1);
          q2 = wave_sum63(q2);
          if (lane == 63) {
            float* yp = ybase + t * NO;
            yp[0] = q0 + bo0;
            yp[1] = q1 + bo1;
            yp[2] = q2 + bo2;
          }
        }
      }
    }
    __syncthreads();
  }

  // h_last = h_{T-1}
  if (wid == 0) {
    float4* hp = (float4*)(out_h + (size_t)b * NH);
    hp[lane] = make_float4(hv[0], hv[1], hv[2], hv[3]);
    hp[64 + lane] = make_float4(hv[4], hv[5], hv[6], hv[7]);
  }
}

extern "C" void kernel_launch(void* const* d_in, const int* in_sizes, int n_in,
                              void* d_out, int out_size, void* d_ws, size_t ws_size,
                              hipStream_t stream) {
  const float* x      = (const float*)d_in[0];
  const float* hidden = (const float*)d_in[1];
  const float* U      = (const float*)d_in[2];
  const float* V      = (const float*)d_in[3];
  const float* W_in   = (const float*)d_in[4];
  const float* b_in   = (const float*)d_in[5];
  const float* W_out  = (const float*)d_in[6];
  const float* b_out  = (const float*)d_in[7];

  float* out = (float*)d_out;
  float* out_y = out;                                  // [B,T,3]
  float* out_h = out + (size_t)NB * NT * NO;           // [B,512]
  float* out_r = out_h + (size_t)NB * NH;              // [B,T,512]

  hipLaunchKernelGGL(lowrank_rnn_kernel, dim3(NB), dim3(256), 0, stream,
                     x, hidden, U, V, W_in, b_in, W_out, b_out,
                     out_y, out_h, out_r);
}